// Round 1
// baseline (454.072 us; speedup 1.0000x reference)
//
#include <hip/hip_runtime.h>
#include <stdint.h>

// Problem dims
#define BDIM 8
#define CDIM 32
#define NDIM 512
#define TDIM 168
#define KG   2048          // GEMM K = 4 slices * 512 nodes
#define NJ   43008         // 256 (b,o) * 168 l
#define ALPHA_ 0.05f
#define BETA_  0.95f

typedef __attribute__((ext_vector_type(8))) short short8;
typedef __attribute__((ext_vector_type(4))) float f32x4;
typedef __attribute__((ext_vector_type(4))) unsigned int u32x4;

__device__ __forceinline__ unsigned short f2bf(float f) {
  union { float f; unsigned int u; } v; v.f = f;
  unsigned int r = v.u + 0x7fffu + ((v.u >> 16) & 1u);
  return (unsigned short)(r >> 16);
}
__device__ __forceinline__ float bf2f(unsigned short h) {
  union { unsigned int u; float f; } v; v.u = ((unsigned int)h) << 16;
  return v.f;
}
__device__ __forceinline__ void gload_lds16(const void* g, void* l) {
  __builtin_amdgcn_global_load_lds((const __attribute__((address_space(1))) void*)g,
                                   (__attribute__((address_space(3))) void*)l, 16, 0, 0);
}

// ---- prep: row sums of (adp + I) and (adp^T + I) ----
__global__ void gc_prep(const float* __restrict__ adp, float* __restrict__ rs) {
  int v = blockIdx.x, t = threadIdx.x;
  float sA = 0.f, sB = 0.f;
  for (int w = t; w < NDIM; w += 256) { sA += adp[v * NDIM + w]; sB += adp[w * NDIM + v]; }
  __shared__ float red[2][256];
  red[0][t] = sA; red[1][t] = sB; __syncthreads();
  for (int s = 128; s > 0; s >>= 1) {
    if (t < s) { red[0][t] += red[0][t + s]; red[1][t] += red[1][t + s]; }
    __syncthreads();
  }
  if (t == 0) { rs[v] = 1.f + red[0][0]; rs[NDIM + v] = 1.f + red[1][0]; }
}

// ---- build A (slice 0) and A' (slice 2) into G[n][m], plus fp32 copies ----
__global__ void gc_build(const float* __restrict__ adp, const float* __restrict__ rs,
                         float* __restrict__ Af, unsigned short* __restrict__ G) {
  int v = blockIdx.x, t = threadIdx.x;
  float ra = 1.f / rs[v], rb = 1.f / rs[NDIM + v];
  for (int w = t; w < NDIM; w += 256) {
    float d = (v == w) ? 1.f : 0.f;
    float a  = (adp[v * NDIM + w] + d) * ra;   // A[v][w]
    float a2 = (adp[w * NDIM + v] + d) * rb;   // A'[v][w]
    Af[(size_t)v * NDIM + w] = a;
    Af[(size_t)NDIM * NDIM + (size_t)v * NDIM + w] = a2;
    G[(size_t)v * KG + w] = f2bf(a);
    G[(size_t)v * KG + 1024 + w] = f2bf(a2);
  }
}

// ---- A^2 (slice 1) and A'^2 (slice 3) ----
__global__ void gc_sq(const float* __restrict__ Af, unsigned short* __restrict__ G) {
  int mat = blockIdx.x >> 6, tile = blockIdx.x & 63;
  int v0 = (tile >> 3) * 64, w0 = (tile & 7) * 64;
  const float* M = Af + (size_t)mat * NDIM * NDIM;
  __shared__ float T1[64][64];
  __shared__ float T2[64][65];
  int t = threadIdx.x;
  float acc[4][4] = {};
  for (int u0 = 0; u0 < NDIM; u0 += 64) {
    for (int idx = t; idx < 64 * 64; idx += 256) {
      int r = idx >> 6, c2 = idx & 63;
      T1[r][c2] = M[(size_t)(v0 + r) * NDIM + u0 + c2];
      T2[r][c2] = M[(size_t)(u0 + r) * NDIM + w0 + c2];
    }
    __syncthreads();
    int ty = t >> 4, tx = t & 15;
    for (int u = 0; u < 64; ++u) {
      float b0 = T2[u][tx * 4], b1v = T2[u][tx * 4 + 1], b2v = T2[u][tx * 4 + 2], b3v = T2[u][tx * 4 + 3];
      #pragma unroll
      for (int i = 0; i < 4; ++i) {
        float a = T1[ty * 4 + i][u];
        acc[i][0] += a * b0; acc[i][1] += a * b1v; acc[i][2] += a * b2v; acc[i][3] += a * b3v;
      }
    }
    __syncthreads();
  }
  int ty = t >> 4, tx = t & 15;
  size_t colbase = (size_t)(mat ? 3 : 1) * 512;
  for (int i = 0; i < 4; ++i)
    for (int j = 0; j < 4; ++j)
      G[(size_t)(v0 + ty * 4 + i) * KG + colbase + (w0 + tx * 4 + j)] = f2bf(acc[i][j]);
}

// ---- folded channel-mix matrices: U[160][32] rows = {U1,U2,V1,V2,U0'}; bias = b1+b2 ----
__global__ void gc_ucat(const float* __restrict__ W1, const float* __restrict__ b1,
                        const float* __restrict__ W2, const float* __restrict__ b2,
                        float* __restrict__ U, float* __restrict__ bias) {
  int t = threadIdx.x;
  for (int idx = t; idx < 160 * 32; idx += 256) {
    int ko = idx >> 5, c = idx & 31, o = ko & 31, s = ko >> 5;
    float v;
    if (s == 0)      v = BETA_ * (W1[o * 96 + 32 + c] + ALPHA_ * W1[o * 96 + 64 + c]);
    else if (s == 1) v = BETA_ * BETA_ * W1[o * 96 + 64 + c];
    else if (s == 2) v = BETA_ * (W2[o * 96 + 32 + c] + ALPHA_ * W2[o * 96 + 64 + c]);
    else if (s == 3) v = BETA_ * BETA_ * W2[o * 96 + 64 + c];
    else             v = W1[o * 96 + c] + ALPHA_ * (W1[o * 96 + 32 + c] + W1[o * 96 + 64 + c])
                       + W2[o * 96 + c] + ALPHA_ * (W2[o * 96 + 32 + c] + W2[o * 96 + 64 + c]);
    U[idx] = v;
  }
  if (t < 32) bias[t] = b1[t] + b2[t];
}

// ---- channel-mix pass: P[kb][j][8] bf16 (GEMM B pre-swizzled) and R0[bo][n][l] bf16 ----
// grid 1536 = 8 b * 32 wt(16 nodes) * 6 lt(32 l); 256 threads
__global__ __launch_bounds__(256) void gc_mix(const float* __restrict__ x,
    const float* __restrict__ U, unsigned short* __restrict__ Pg,
    unsigned short* __restrict__ R0) {
  __shared__ __align__(16) float X[16384];   // [c 32][w 16][l 32] f32, 64KB
  int bid = blockIdx.x;
  int lt = bid % 6, wt = (bid / 6) & 31, b = bid / 192;
  int l0 = lt * 32, w0 = wt * 16;
  int tid = threadIdx.x, wid = tid >> 6, lane = tid & 63;

  // stage x[b][:][w0:w0+16][l0:l0+32] -> LDS (clamped l for tail tile)
  #pragma unroll
  for (int q = 0; q < 16; ++q) {
    int ii = wid * 16 + q;               // 0..63 instrs
    int row = ii * 8 + (lane >> 3);      // 0..511 -> (c, wl)
    int c = row >> 4, wl = row & 15;
    int sl = l0 + (lane & 7) * 4; if (sl > 164) sl = 164;
    const float* src = x + (size_t)((b * 32 + c) * 512 + w0 + wl) * 168 + sl;
    gload_lds16(src, X + ii * 256);
  }
  __syncthreads();

  int wh = lane >> 5, lq = lane & 31;
  int xoff = wh * 256 + lq;
  int l = l0 + lq;
  bool valid = l < 168;

  for (int g = 0; g < 10; ++g) {
    int ko0 = __builtin_amdgcn_readfirstlane(wid * 40 + g * 4);
    int slice = ko0 >> 5;
    float a0[8] = {}, a1[8] = {}, a2[8] = {}, a3[8] = {};
    for (int c = 0; c < 32; ++c) {
      float u0 = U[(ko0    ) * 32 + c];
      float u1 = U[(ko0 + 1) * 32 + c];
      float u2 = U[(ko0 + 2) * 32 + c];
      float u3 = U[(ko0 + 3) * 32 + c];
      const float* xp = X + c * 512 + xoff;
      #pragma unroll
      for (int w2 = 0; w2 < 8; ++w2) {
        float xv = xp[w2 * 32];
        a0[w2] += u0 * xv; a1[w2] += u1 * xv; a2[w2] += u2 * xv; a3[w2] += u3 * xv;
      }
    }
    if (!valid) continue;
    if (slice == 4) {
      // R0 direct stores: layout [bo][n][l]
      int o0 = ko0 & 31;
      #pragma unroll
      for (int w2 = 0; w2 < 8; ++w2) {
        int n = w0 + wh * 8 + w2;
        size_t base = ((size_t)(b * 32 + o0) * 512 + n) * 168 + l;
        R0[base                        ] = f2bf(a0[w2]);
        R0[base + (size_t)1 * 512 * 168] = f2bf(a1[w2]);
        R0[base + (size_t)2 * 512 * 168] = f2bf(a2[w2]);
        R0[base + (size_t)3 * 512 * 168] = f2bf(a3[w2]);
      }
    } else {
      // each lane owns the 8 consecutive-w values of one 16B chunk of Pg
      int kbg = slice * 64 + wt * 2 + wh;       // global m>>3
      size_t jbase = (size_t)(b * 32) * 168 + l;
      #define PSTORE(AA, K) { \
        unsigned int p0 = (unsigned)f2bf(AA[0]) | ((unsigned)f2bf(AA[1]) << 16); \
        unsigned int p1 = (unsigned)f2bf(AA[2]) | ((unsigned)f2bf(AA[3]) << 16); \
        unsigned int p2 = (unsigned)f2bf(AA[4]) | ((unsigned)f2bf(AA[5]) << 16); \
        unsigned int p3 = (unsigned)f2bf(AA[6]) | ((unsigned)f2bf(AA[7]) << 16); \
        int o = (ko0 + (K)) & 31; \
        u32x4 vv = {p0, p1, p2, p3}; \
        *(u32x4*)(Pg + ((size_t)kbg * NJ + jbase + (size_t)o * 168) * 8) = vv; }
      PSTORE(a0, 0) PSTORE(a1, 1) PSTORE(a2, 2) PSTORE(a3, 3)
      #undef PSTORE
    }
  }
}

// ---- main GEMM: C[512 n][43008 j] = G[512][2048] * P[2048][43008], + R0 + bias ----
// 1344 blocks (336 jt * 4 nt), 256 threads (4 waves 2x2), 128x128 tile, BK=32
__global__ __launch_bounds__(256, 2) void gc_gemm(const unsigned short* __restrict__ G,
    const unsigned short* __restrict__ Pg, const unsigned short* __restrict__ R0,
    const float* __restrict__ bias, float* __restrict__ out) {
  int bid = blockIdx.x;
  int swz = (bid & 7) * 168 + (bid >> 3);     // XCD-chunked bijective swizzle (1344 % 8 == 0)
  int nt = swz & 3, jt = swz >> 2;
  int n0 = nt * 128, j0 = jt * 128;

  __shared__ __align__(16) unsigned short Ab[2][4096];  // [kb 4][row 128][8]
  __shared__ __align__(16) unsigned short Bb[2][4096];
  int tid = threadIdx.x, wid = tid >> 6, lane = tid & 63;
  int wn = wid >> 1, wj = wid & 1;

  f32x4 acc[4][4] = {};

  auto stage = [&](int buf, int t) {
    int m0 = t * 32;
    #pragma unroll
    for (int q = 0; q < 4; ++q) {
      int ii = wid * 4 + q;             // 0..7 A, 8..15 B
      if (ii < 8) {
        int kb = ii >> 1, row = (ii & 1) * 64 + lane;
        const unsigned short* src = G + (size_t)(n0 + row) * KG + m0 + kb * 8;
        gload_lds16(src, &Ab[buf][ii * 512]);
      } else {
        int i2 = ii - 8;
        int kb = i2 >> 1, row = (i2 & 1) * 64 + lane;
        const unsigned short* src = Pg + ((size_t)((m0 >> 3) + kb) * NJ + (j0 + row)) * 8;
        gload_lds16(src, &Bb[buf][i2 * 512]);
      }
    }
  };

  stage(0, 0);
  __syncthreads();
  int abase = (lane >> 4) * 1024 + (wn * 64 + (lane & 15)) * 8;
  int bbase = (lane >> 4) * 1024 + (wj * 64 + (lane & 15)) * 8;
  for (int t = 0; t < 64; ++t) {
    int cur = t & 1;
    if (t < 63) stage(cur ^ 1, t + 1);
    short8 aF[4], bF[4];
    #pragma unroll
    for (int f = 0; f < 4; ++f) aF[f] = *(const short8*)&Ab[cur][abase + f * 128];
    #pragma unroll
    for (int f = 0; f < 4; ++f) bF[f] = *(const short8*)&Bb[cur][bbase + f * 128];
    #pragma unroll
    for (int i = 0; i < 4; ++i)
      #pragma unroll
      for (int j = 0; j < 4; ++j)
        acc[i][j] = __builtin_amdgcn_mfma_f32_16x16x32_bf16(aF[i], bF[j], acc[i][j], 0, 0, 0);
    __syncthreads();
  }

  // epilogue: out[(bo*512+n)*168+l] = acc + R0 + bias[o]
  #pragma unroll
  for (int fj = 0; fj < 4; ++fj) {
    int jj = j0 + wj * 64 + fj * 16 + (lane & 15);
    int bo = jj / 168;
    int l = jj - bo * 168;
    float bs = bias[bo & 31];
    size_t obase = (size_t)bo * 512 * 168 + l;
    #pragma unroll
    for (int fi = 0; fi < 4; ++fi) {
      #pragma unroll
      for (int r = 0; r < 4; ++r) {
        int n = n0 + wn * 64 + fi * 16 + (lane >> 4) * 4 + r;
        size_t idx = obase + (size_t)n * 168;
        out[idx] = acc[fi][fj][r] + bf2f(R0[idx]) + bs;
      }
    }
  }
}

extern "C" void kernel_launch(void* const* d_in, const int* in_sizes, int n_in,
                              void* d_out, int out_size, void* d_ws, size_t ws_size,
                              hipStream_t stream) {
  const float* x   = (const float*)d_in[0];
  const float* adp = (const float*)d_in[1];
  const float* W1  = (const float*)d_in[2];
  const float* b1  = (const float*)d_in[3];
  const float* W2  = (const float*)d_in[4];
  const float* b2  = (const float*)d_in[5];
  float* out = (float*)d_out;

  char* w = (char*)d_ws;
  unsigned short* Pg  = (unsigned short*)(w);                  // 176,160,768 B
  unsigned short* R0  = (unsigned short*)(w + 176160768ULL);   //  44,040,192 B
  unsigned short* G   = (unsigned short*)(w + 220200960ULL);   //   2,097,152 B
  float* Af           = (float*)(w + 222298112ULL);            //   2,097,152 B
  float* rs           = (float*)(w + 224395264ULL);            //       4,096 B
  float* U            = (float*)(w + 224399360ULL);            //      20,480 B
  float* bias         = (float*)(w + 224419840ULL);            //         128 B
  if (ws_size < 224419968ULL) return;                          // need ~214 MiB

  gc_prep<<<512, 256, 0, stream>>>(adp, rs);
  gc_build<<<512, 256, 0, stream>>>(adp, rs, Af, G);
  gc_sq<<<128, 256, 0, stream>>>(Af, G);
  gc_ucat<<<1, 256, 0, stream>>>(W1, b1, W2, b2, U, bias);
  gc_mix<<<1536, 256, 0, stream>>>(x, U, Pg, R0);
  gc_gemm<<<1344, 256, 0, stream>>>(G, Pg, R0, bias, out);
}